// Round 11
// baseline (112.676 us; speedup 1.0000x reference)
//
#include <hip/hip_runtime.h>

#define BB 4096
#define TN 512
#define IN 13
#define HN 7
#define FFD 512
#define CT 32            // timesteps per chunk
#define NCK (TN / CT)    // 16 chunks
#define GPB 2            // chains per block

#if defined(__has_builtin)
#  if __has_builtin(__builtin_amdgcn_permlane16_swap)
#    define HAVE_PL16 1
#  endif
#endif

// quad broadcast (quad_perm): dst[l] = src[quadbase + q]
#define QB(v, q)    __int_as_float(__builtin_amdgcn_mov_dpp(__float_as_int(v), (q)*0x55, 0xF, 0xF, true))
// DPP row rotate by n lanes within each 16-lane row (direction probed at runtime)
#define RORF(v, n)  __int_as_float(__builtin_amdgcn_mov_dpp(__float_as_int(v), 0x120 + (n), 0xF, 0xF, true))

// Exchange 16-lane rows between a and b -> two DISTINCT result registers.
__device__ __forceinline__ void rowswap(float& a, float& b) {
#ifdef HAVE_PL16
    auto r = __builtin_amdgcn_permlane16_swap(__float_as_uint(a), __float_as_uint(b),
                                              false, false);
    a = __uint_as_float(r[0]);
    b = __uint_as_float(r[1]);
#else
    float ta, tb;
    asm volatile("v_mov_b32 %0, %2\n"
                 "v_mov_b32 %1, %3\n"
                 "s_nop 1\n"
                 "v_permlane16_swap_b32 %0, %1"
                 : "=&v"(ta), "=&v"(tb)
                 : "v"(a), "v"(b));
    a = ta; b = tb;
#endif
}

// packed dual-fp32 FMA: d.{x,y} = a.{x,y}*b.{x,y} + c.{x,y}
__device__ __forceinline__ float2 pkfma(float2 a, float2 b, float2 c) {
    float2 d;
    asm("v_pk_fma_f32 %0, %1, %2, %3" : "=v"(d) : "v"(a), "v"(b), "v"(c));
    return d;
}

__global__ __launch_bounds__(128, 4)
void lstm_fused(const float* __restrict__ x,
                const float* __restrict__ w_ih,
                const float* __restrict__ w_hh,
                const float* __restrict__ b_ih,
                const float* __restrict__ b_hh,
                const float* __restrict__ fc1_w,
                const float* __restrict__ fc1_b,
                const float* __restrict__ fc_w,
                const float* __restrict__ fc_b,
                float* __restrict__ out)
{
    __shared__ float2 xd2[2][CT/2][64];   // scaled gate pre-activation, step-pairs, dbuf (16 KB)
    __shared__ float  xs[IN][GPB][CT];    // staged x, COLUMN-major (col, chain, step)

    const int tid  = threadIdx.x;
    const int wid  = tid >> 6;            // 0 = consumer wave, 1 = producer wave
    const int l64  = tid & 63;
    const int grp  = l64 >> 5;
    const int lane = l64 & 31;
    const int b    = blockIdx.x * GPB + grp;

    // gate layout: quad j = hidden unit j, tau = lane&3 (0=i,1=f,2=g,3=o)
    const int tau = lane & 3;
    const int ju  = lane >> 2;
    const int jj  = (ju < HN) ? ju : (HN - 1);
    const int row = tau * HN + jj;
    const int jr  = ju & 3;

    const float L2E  = 1.4426950408889634f;
    const bool  is_tanh = (tau == 2);
    const float kmul = is_tanh ? (-2.0f * L2E) : (-L2E);  // folded into weights
    const float sc   = is_tanh ?  2.0f : 1.0f;
    const float offc = is_tanh ? -1.0f : 0.0f;

    // ---------------- runtime convention probes (one-time, all-VALU) ----------------
    const int pr = __builtin_amdgcn_mov_dpp(l64, 0x124, 0xF, 0xF, true);
    const bool ror_plus = ((pr & 15) == ((l64 + 4) & 15));
    float paf = __int_as_float(l64);
    float pbf = __int_as_float(l64 + 64);
    rowswap(paf, pbf);
    const int pa = __float_as_int(paf) & 63;
    const bool a_even = (((pa >> 4) & 1) == 0);

    // ---------------- producer-only state ----------------
    float2 w2[IN];
    float2 bias2;
    float  p[IN];
    const float* xbase = x + (long)b * TN * IN;

    // ---------------- consumer-only state ----------------
    // slot k of family A holds h_{(jr+dk)&3} (low family if a_even, else high);
    // dk = ror_plus ? k : (4-k)&3. Weights pre-permuted accordingly; packed pairs.
    float2 wA01, wA23, wB01, wB23;

    if (wid == 1) {
#pragma unroll
        for (int i = 0; i < IN; ++i) {
            const float w = kmul * w_ih[row * IN + i];
            w2[i] = make_float2(w, w);
        }
        const float bsum = kmul * (b_ih[row] + b_hh[row]);
        bias2 = make_float2(bsum, bsum);
    } else {
        float wA[4], wB[4];
#pragma unroll
        for (int k = 0; k < 4; ++k) {
            const int dk  = ror_plus ? k : ((4 - k) & 3);
            const int cL  = (jr + dk) & 3;
            const int cH  = 4 + ((jr + dk) & 3);
            const float wL = kmul * w_hh[row * HN + cL];
            const float wH = (cH < HN) ? kmul * w_hh[row * HN + cH] : 0.0f;
            wA[k] = a_even ? wL : wH;
            wB[k] = a_even ? wH : wL;
        }
        wA01 = make_float2(wA[0], wA[1]);
        wA23 = make_float2(wA[2], wA[3]);
        wB01 = make_float2(wB[0], wB[1]);
        wB23 = make_float2(wB[2], wB[3]);
        __builtin_amdgcn_s_setprio(1);    // favor latency-critical recurrence waves
    }

    float2 A01 = make_float2(0.f, 0.f), A23 = make_float2(0.f, 0.f);
    float2 B01 = make_float2(0.f, 0.f), B23 = make_float2(0.f, 0.f);
    float cval = 0.0f;

    // producer micro-ops
#define LOADP(ck) do {                                                        \
        const float* _s = xbase + (long)((ck) * CT + lane) * IN;              \
        _Pragma("unroll")                                                     \
        for (int _i = 0; _i < IN; ++_i) p[_i] = _s[_i];                       \
    } while (0)
#define COMMITP() do {                                                        \
        _Pragma("unroll")                                                     \
        for (int _i = 0; _i < IN; ++_i) xs[_i][grp][lane] = p[_i];            \
    } while (0)
#define PROJECT(ck) do {                                                      \
        const int _buf = (ck) & 1;                                            \
        _Pragma("unroll")                                                     \
        for (int _q = 0; _q < CT; _q += 4) {                                  \
            float2 _aA = bias2, _aB = bias2;                                  \
            _Pragma("unroll")                                                 \
            for (int _i = 0; _i < IN; ++_i) {                                 \
                const float4 _xv = *(const float4*)&xs[_i][grp][_q];          \
                _aA = pkfma(w2[_i], make_float2(_xv.x, _xv.y), _aA);          \
                _aB = pkfma(w2[_i], make_float2(_xv.z, _xv.w), _aB);          \
            }                                                                 \
            xd2[_buf][(_q >> 1) + 0][l64] = _aA;                              \
            xd2[_buf][(_q >> 1) + 1][l64] = _aB;                              \
        }                                                                     \
    } while (0)

    // ---------------- prologue ----------------
    if (wid == 1) {
        LOADP(0);
        COMMITP();
        LOADP(1);
        PROJECT(0);
    }
    __syncthreads();

    // ---------------- main pipeline ----------------
    for (int ck = 0; ck < NCK; ++ck) {
        if (wid == 1) {
            const int nk = ck + 1;
            if (nk < NCK) {
                COMMITP();                     // p holds chunk nk
                if (nk + 1 < NCK) LOADP(nk + 1);
                PROJECT(nk);
            }
        } else {
            const int buf = ck & 1;
            float2 xr2[CT / 2];
#pragma unroll
            for (int pq = 0; pq < CT / 2; ++pq) xr2[pq] = xd2[buf][pq][l64];

#pragma unroll
            for (int s = 0; s < CT; ++s) {
                const float xr = (s & 1) ? xr2[s >> 1].y : xr2[s >> 1].x;
                // packed h-dot: 4 pkfma + 2 adds (pre-scaled by kmul)
                float2 t = pkfma(wA01, A01, make_float2(0.f, 0.f));
                t = pkfma(wA23, A23, t);
                t = pkfma(wB01, B01, t);
                t = pkfma(wB23, B23, t);
                const float sg = (t.x + t.y) + xr;

                float e   = __builtin_amdgcn_exp2f(sg);
                float val = fmaf(__builtin_amdgcn_rcpf(1.0f + e), sc, offc);

                const float iv = QB(val, 0);
                const float fv = QB(val, 1);
                const float gv = QB(val, 2);
                const float ov = QB(val, 3);

                cval = fmaf(fv, cval, iv * gv);
                float e2 = __builtin_amdgcn_exp2f(-2.0f * L2E * cval);
                float th = fmaf(__builtin_amdgcn_rcpf(1.0f + e2), 2.0f, -1.0f);
                const float hq = ov * th;

                // VALU-only h broadcast straight into packed halves
                float aa = hq, bb = hq;
                rowswap(aa, bb);
                A01.x = aa;           B01.x = bb;
                A01.y = RORF(aa, 4);  B01.y = RORF(bb, 4);
                A23.x = RORF(aa, 8);  B23.x = RORF(bb, 8);
                A23.y = RORF(aa, 12); B23.y = RORF(bb, 12);
            }
        }
        __syncthreads();
    }

    if (wid == 1) return;

    // epilogue (consumer): relu -> fc1(512x7) -> relu -> fc(1x512)
    // A01.x/B01.x hold h_{jr} (low/high family per a_even); gather via shfl.
    const float hA = a_even ? A01.x : B01.x;   // low-family  h_{jr}
    const float hB = a_even ? B01.x : A01.x;   // high-family h_{4+jr}
    float hb[HN];
#pragma unroll
    for (int j = 0; j < 4; ++j) hb[j] = fmaxf(__shfl(hA, 4 * j, 32), 0.0f);
#pragma unroll
    for (int j = 0; j < 3; ++j) hb[4 + j] = fmaxf(__shfl(hB, 4 * j, 32), 0.0f);

    float acc = 0.0f;
#pragma unroll
    for (int k = 0; k < FFD / 32; ++k) {
        const int r = lane + (k << 5);
        float s = fc1_b[r];
#pragma unroll
        for (int j = 0; j < HN; ++j) s = fmaf(fc1_w[r * HN + j], hb[j], s);
        s = fmaxf(s, 0.0f);
        acc = fmaf(fc_w[r], s, acc);
    }
#pragma unroll
    for (int o = 16; o >= 1; o >>= 1) acc += __shfl_xor(acc, o, 32);
    if (lane == 0) out[b] = acc + fc_b[0];
}

extern "C" void kernel_launch(void* const* d_in, const int* in_sizes, int n_in,
                              void* d_out, int out_size, void* d_ws, size_t ws_size,
                              hipStream_t stream) {
    const float* x     = (const float*)d_in[0];
    const float* w_ih  = (const float*)d_in[1];
    const float* w_hh  = (const float*)d_in[2];
    const float* b_ih  = (const float*)d_in[3];
    const float* b_hh  = (const float*)d_in[4];
    const float* fc1_w = (const float*)d_in[5];
    const float* fc1_b = (const float*)d_in[6];
    const float* fc_w  = (const float*)d_in[7];
    const float* fc_b  = (const float*)d_in[8];
    float* out = (float*)d_out;

    dim3 grid(BB / GPB);   // 2048 blocks x (1 consumer + 1 producer wave)
    dim3 block(128);
    hipLaunchKernelGGL(lstm_fused, grid, block, 0, stream,
                       x, w_ih, w_hh, b_ih, b_hh, fc1_w, fc1_b, fc_w, fc_b, out);
}

// Round 12
// 109.117 us; speedup vs baseline: 1.0326x; 1.0326x over previous
//
#include <hip/hip_runtime.h>

#define BB 4096
#define TN 512
#define IN 13
#define HN 7
#define FFD 512
#define CT 32            // timesteps per chunk
#define NCK (TN / CT)    // 16 chunks
#define GPB 4            // chains per block (2 per lane-group x 2 register sets)

#if defined(__has_builtin)
#  if __has_builtin(__builtin_amdgcn_permlane16_swap)
#    define HAVE_PL16 1
#  endif
#endif

// quad broadcast (quad_perm): dst[l] = src[quadbase + q]
#define QB(v, q)    __int_as_float(__builtin_amdgcn_mov_dpp(__float_as_int(v), (q)*0x55, 0xF, 0xF, true))
// DPP row rotate by n lanes within each 16-lane row (direction probed at runtime)
#define RORF(v, n)  __int_as_float(__builtin_amdgcn_mov_dpp(__float_as_int(v), 0x120 + (n), 0xF, 0xF, true))

// Exchange 16-lane rows between a and b -> two DISTINCT result registers.
__device__ __forceinline__ void rowswap(float& a, float& b) {
#ifdef HAVE_PL16
    auto r = __builtin_amdgcn_permlane16_swap(__float_as_uint(a), __float_as_uint(b),
                                              false, false);
    a = __uint_as_float(r[0]);
    b = __uint_as_float(r[1]);
#else
    float ta, tb;
    asm volatile("v_mov_b32 %0, %2\n"
                 "v_mov_b32 %1, %3\n"
                 "s_nop 1\n"
                 "v_permlane16_swap_b32 %0, %1"
                 : "=&v"(ta), "=&v"(tb)
                 : "v"(a), "v"(b));
    a = ta; b = tb;
#endif
}

// packed dual-fp32 FMA: d.{x,y} = a.{x,y}*b.{x,y} + c.{x,y}
__device__ __forceinline__ float2 pkfma(float2 a, float2 b, float2 c) {
    float2 d;
    asm("v_pk_fma_f32 %0, %1, %2, %3" : "=v"(d) : "v"(a), "v"(b), "v"(c));
    return d;
}

__global__ __launch_bounds__(128, 2)
void lstm_fused(const float* __restrict__ x,
                const float* __restrict__ w_ih,
                const float* __restrict__ w_hh,
                const float* __restrict__ b_ih,
                const float* __restrict__ b_hh,
                const float* __restrict__ fc1_w,
                const float* __restrict__ fc1_b,
                const float* __restrict__ fc_w,
                const float* __restrict__ fc_b,
                float* __restrict__ out)
{
    __shared__ float2 xd2[2][2][CT/2][64];  // [buf][set][step-pair][gate-col] (32 KB)
    __shared__ float  xs[IN][GPB][CT];      // staged x, col-major (6.5 KB)

    const int tid  = threadIdx.x;
    const int wid  = tid >> 6;            // 0 = consumer wave, 1 = producer wave
    const int l64  = tid & 63;
    const int grp  = l64 >> 5;            // chain-group within sets
    const int lane = l64 & 31;
    const int bbase = blockIdx.x * GPB;
    const int bu = bbase + grp;           // u-chain (set 0)
    const int bv = bbase + 2 + grp;       // v-chain (set 1)

    // gate layout: quad j = hidden unit j, tau = lane&3 (0=i,1=f,2=g,3=o)
    const int tau = lane & 3;
    const int ju  = lane >> 2;
    const int jj  = (ju < HN) ? ju : (HN - 1);
    const int row = tau * HN + jj;
    const int jr  = ju & 3;

    const float L2E  = 1.4426950408889634f;
    const bool  is_tanh = (tau == 2);
    const float kmul = is_tanh ? (-2.0f * L2E) : (-L2E);  // folded into weights
    const float sc   = is_tanh ?  2.0f : 1.0f;
    const float offc = is_tanh ? -1.0f : 0.0f;

    // ---------------- runtime convention probes (one-time, all-VALU) ----------------
    const int pr = __builtin_amdgcn_mov_dpp(l64, 0x124, 0xF, 0xF, true);
    const bool ror_plus = ((pr & 15) == ((l64 + 4) & 15));
    float paf = __int_as_float(l64);
    float pbf = __int_as_float(l64 + 64);
    rowswap(paf, pbf);
    const int pa = __float_as_int(paf) & 63;
    const bool a_even = (((pa >> 4) & 1) == 0);

    // ---------------- producer-only state ----------------
    float2 w2[IN];
    float2 bias2;
    float  p0[IN], p1[IN];
    const float* xu = x + (long)bu * TN * IN;
    const float* xv = x + (long)bv * TN * IN;

    // ---------------- consumer-only state ----------------
    float wA[4], wB[4];

    if (wid == 1) {
#pragma unroll
        for (int i = 0; i < IN; ++i) {
            const float w = kmul * w_ih[row * IN + i];
            w2[i] = make_float2(w, w);
        }
        const float bsum = kmul * (b_ih[row] + b_hh[row]);
        bias2 = make_float2(bsum, bsum);
    } else {
#pragma unroll
        for (int k = 0; k < 4; ++k) {
            const int dk  = ror_plus ? k : ((4 - k) & 3);
            const int cL  = (jr + dk) & 3;
            const int cH  = 4 + ((jr + dk) & 3);
            const float wL = kmul * w_hh[row * HN + cL];
            const float wH = (cH < HN) ? kmul * w_hh[row * HN + cH] : 0.0f;
            wA[k] = a_even ? wL : wH;
            wB[k] = a_even ? wH : wL;
        }
    }

    // two independent chain register sets (u, v)
    float au0=0.f, au1=0.f, au2=0.f, au3=0.f, bu0=0.f, bu1=0.f, bu2=0.f, bu3=0.f, cu=0.f;
    float av0=0.f, av1=0.f, av2=0.f, av3=0.f, bv0=0.f, bv1=0.f, bv2=0.f, bv3=0.f, cv=0.f;

    // producer micro-ops
#define LOADP(ck) do {                                                        \
        const float* _su = xu + (long)((ck) * CT + lane) * IN;                \
        const float* _sv = xv + (long)((ck) * CT + lane) * IN;                \
        _Pragma("unroll")                                                     \
        for (int _i = 0; _i < IN; ++_i) { p0[_i] = _su[_i]; p1[_i] = _sv[_i]; } \
    } while (0)
#define COMMITP() do {                                                        \
        _Pragma("unroll")                                                     \
        for (int _i = 0; _i < IN; ++_i) {                                     \
            xs[_i][grp][lane]     = p0[_i];                                   \
            xs[_i][2 + grp][lane] = p1[_i];                                   \
        }                                                                     \
    } while (0)
#define PROJECT(ck) do {                                                      \
        const int _buf = (ck) & 1;                                            \
        _Pragma("unroll")                                                     \
        for (int _set = 0; _set < 2; ++_set) {                                \
            const int _cs = _set * 2 + grp;                                   \
            _Pragma("unroll")                                                 \
            for (int _q = 0; _q < CT; _q += 4) {                              \
                float2 _aA = bias2, _aB = bias2;                              \
                _Pragma("unroll")                                             \
                for (int _i = 0; _i < IN; ++_i) {                             \
                    const float4 _xv = *(const float4*)&xs[_i][_cs][_q];      \
                    _aA = pkfma(w2[_i], make_float2(_xv.x, _xv.y), _aA);      \
                    _aB = pkfma(w2[_i], make_float2(_xv.z, _xv.w), _aB);      \
                }                                                             \
                xd2[_buf][_set][(_q >> 1) + 0][l64] = _aA;                    \
                xd2[_buf][_set][(_q >> 1) + 1][l64] = _aB;                    \
            }                                                                 \
        }                                                                     \
    } while (0)

    // one LSTM step on one register set (all-VALU; DPP broadcast)
#define STEP(xr, A0, A1, A2, A3, B0, B1, B2, B3, CV) do {                     \
        float _t0 = fmaf(wA[0], A0, (xr));                                    \
        _t0 = fmaf(wA[1], A1, _t0);                                           \
        _t0 = fmaf(wA[2], A2, _t0);                                           \
        _t0 = fmaf(wA[3], A3, _t0);                                           \
        float _t1 = wB[0] * B0;                                               \
        _t1 = fmaf(wB[1], B1, _t1);                                           \
        _t1 = fmaf(wB[2], B2, _t1);                                           \
        _t1 = fmaf(wB[3], B3, _t1);                                           \
        const float _sg = _t0 + _t1;                                          \
        float _e   = __builtin_amdgcn_exp2f(_sg);                             \
        float _val = fmaf(__builtin_amdgcn_rcpf(1.0f + _e), sc, offc);        \
        const float _iv = QB(_val, 0);                                        \
        const float _fv = QB(_val, 1);                                        \
        const float _gv = QB(_val, 2);                                        \
        const float _ov = QB(_val, 3);                                        \
        CV = fmaf(_fv, CV, _iv * _gv);                                        \
        float _e2 = __builtin_amdgcn_exp2f(-2.0f * L2E * CV);                 \
        float _th = fmaf(__builtin_amdgcn_rcpf(1.0f + _e2), 2.0f, -1.0f);     \
        const float _hq = _ov * _th;                                          \
        float _aa = _hq, _bb = _hq;                                           \
        rowswap(_aa, _bb);                                                    \
        A0 = _aa;           B0 = _bb;                                         \
        A1 = RORF(_aa, 4);  B1 = RORF(_bb, 4);                                \
        A2 = RORF(_aa, 8);  B2 = RORF(_bb, 8);                                \
        A3 = RORF(_aa, 12); B3 = RORF(_bb, 12);                               \
    } while (0)

    // ---------------- prologue ----------------
    if (wid == 1) {
        LOADP(0);
        COMMITP();
        LOADP(1);
        PROJECT(0);
    }
    __syncthreads();

    // ---------------- main pipeline ----------------
    for (int ck = 0; ck < NCK; ++ck) {
        if (wid == 1) {
            const int nk = ck + 1;
            if (nk < NCK) {
                COMMITP();                     // p holds chunk nk
                if (nk + 1 < NCK) LOADP(nk + 1);
                PROJECT(nk);
            }
        } else {
            const int buf = ck & 1;
#pragma unroll
            for (int hb8 = 0; hb8 < CT / 8; ++hb8) {
                float2 xru[4], xrv[4];
#pragma unroll
                for (int k = 0; k < 4; ++k) {
                    xru[k] = xd2[buf][0][hb8 * 4 + k][l64];
                    xrv[k] = xd2[buf][1][hb8 * 4 + k][l64];
                }
#pragma unroll
                for (int k = 0; k < 4; ++k) {
                    STEP(xru[k].x, au0,au1,au2,au3, bu0,bu1,bu2,bu3, cu);
                    STEP(xrv[k].x, av0,av1,av2,av3, bv0,bv1,bv2,bv3, cv);
                    STEP(xru[k].y, au0,au1,au2,au3, bu0,bu1,bu2,bu3, cu);
                    STEP(xrv[k].y, av0,av1,av2,av3, bv0,bv1,bv2,bv3, cv);
                }
            }
        }
        __syncthreads();
    }

    if (wid == 1) return;

    // epilogue (consumer): relu -> fc1(512x7) -> relu -> fc(1x512), both chains.
    // Slot-0 regs hold h_{jr} of each family (dk(0)=0 under either convention).
    const float hAu = a_even ? au0 : bu0;   // low family  h_{jr}  (chain u)
    const float hBu = a_even ? bu0 : au0;   // high family h_{4+jr}
    const float hAv = a_even ? av0 : bv0;
    const float hBv = a_even ? bv0 : av0;

#pragma unroll
    for (int set = 0; set < 2; ++set) {
        const float hA = set ? hAv : hAu;
        const float hB = set ? hBv : hBu;
        float hb[HN];
#pragma unroll
        for (int j = 0; j < 4; ++j) hb[j] = fmaxf(__shfl(hA, 4 * j, 32), 0.0f);
#pragma unroll
        for (int j = 0; j < 3; ++j) hb[4 + j] = fmaxf(__shfl(hB, 4 * j, 32), 0.0f);

        float acc = 0.0f;
#pragma unroll
        for (int k = 0; k < FFD / 32; ++k) {
            const int r = lane + (k << 5);
            float s = fc1_b[r];
#pragma unroll
            for (int j = 0; j < HN; ++j) s = fmaf(fc1_w[r * HN + j], hb[j], s);
            s = fmaxf(s, 0.0f);
            acc = fmaf(fc_w[r], s, acc);
        }
#pragma unroll
        for (int o = 16; o >= 1; o >>= 1) acc += __shfl_xor(acc, o, 32);
        if (lane == 0) out[set ? bv : bu] = acc + fc_b[0];
    }
}

extern "C" void kernel_launch(void* const* d_in, const int* in_sizes, int n_in,
                              void* d_out, int out_size, void* d_ws, size_t ws_size,
                              hipStream_t stream) {
    const float* x     = (const float*)d_in[0];
    const float* w_ih  = (const float*)d_in[1];
    const float* w_hh  = (const float*)d_in[2];
    const float* b_ih  = (const float*)d_in[3];
    const float* b_hh  = (const float*)d_in[4];
    const float* fc1_w = (const float*)d_in[5];
    const float* fc1_b = (const float*)d_in[6];
    const float* fc_w  = (const float*)d_in[7];
    const float* fc_b  = (const float*)d_in[8];
    float* out = (float*)d_out;

    dim3 grid(BB / GPB);   // 1024 blocks x (1 consumer + 1 producer wave), 4 chains each
    dim3 block(128);
    hipLaunchKernelGGL(lstm_fused, grid, block, 0, stream,
                       x, w_ih, w_hh, b_ih, b_hh, fc1_w, fc1_b, fc_w, fc_b, out);
}

// Round 13
// 105.699 us; speedup vs baseline: 1.0660x; 1.0323x over previous
//
#include <hip/hip_runtime.h>

#define BB 4096
#define TN 512
#define IN 13
#define HN 7
#define FFD 512
#define CT 32            // timesteps per chunk
#define NCK (TN / CT)    // 16 chunks

// lane swizzle broadcast (BitMode, or-mask): src lane = 4j within each 32-group
#define SWZ(v, imm) __int_as_float(__builtin_amdgcn_ds_swizzle(__float_as_int(v), (imm)))
// quad broadcast (quad_perm): dst[l] = src[quadbase + q]
#define QB(v, q)    __int_as_float(__builtin_amdgcn_mov_dpp(__float_as_int(v), (q)*0x55, 0xF, 0xF, true))

// packed dual-fp32 FMA: d.{x,y} = a.{x,y}*b.{x,y} + c.{x,y}
__device__ __forceinline__ float2 pkfma(float2 a, float2 b, float2 c) {
    float2 d;
    asm("v_pk_fma_f32 %0, %1, %2, %3" : "=v"(d) : "v"(a), "v"(b), "v"(c));
    return d;
}

__global__ __launch_bounds__(64, 2)
void lstm_fused(const float* __restrict__ x,
                const float* __restrict__ w_ih,
                const float* __restrict__ w_hh,
                const float* __restrict__ b_ih,
                const float* __restrict__ b_hh,
                const float* __restrict__ fc1_w,
                const float* __restrict__ fc1_b,
                const float* __restrict__ fc_w,
                const float* __restrict__ fc_b,
                float* __restrict__ out)
{
    __shared__ float2 xd2[2][CT/2][64];   // gate pre-activation (kmul-scaled), dbuf (16 KB)
    __shared__ float  xs[IN][2][CT];      // staged x, col-major (3.3 KB)

    const int l64  = threadIdx.x;         // single wave per block
    const int grp  = l64 >> 5;            // chain within block
    const int lane = l64 & 31;
    const int b    = blockIdx.x * 2 + grp;

    // gate layout: quad j = hidden unit j, tau = lane&3 (0=i,1=f,2=g,3=o)
    const int tau = lane & 3;
    const int ju  = lane >> 2;
    const int jj  = (ju < HN) ? ju : (HN - 1);
    const int row = tau * HN + jj;

    const float L2E  = 1.4426950408889634f;
    const bool  is_tanh = (tau == 2);
    const float kmul = is_tanh ? (-2.0f * L2E) : (-L2E);  // folded into weights/bias
    const float sc   = is_tanh ?  2.0f : 1.0f;
    const float offc = is_tanh ? -1.0f : 0.0f;
    const float K2   = -2.0f * L2E;

    // every wave holds BOTH roles' state
    float2 w2[IN];
    float2 bias2;
#pragma unroll
    for (int i = 0; i < IN; ++i) {
        const float w = kmul * w_ih[row * IN + i];
        w2[i] = make_float2(w, w);
    }
    {
        const float bsum = kmul * (b_ih[row] + b_hh[row]);
        bias2 = make_float2(bsum, bsum);
    }
    float whh[HN];
#pragma unroll
    for (int k = 0; k < HN; ++k) whh[k] = kmul * w_hh[row * HN + k];

    float h0 = 0.f, h1 = 0.f, h2 = 0.f, h3 = 0.f, h4 = 0.f, h5 = 0.f, h6 = 0.f;
    float cval = 0.0f;
    float pA[IN], pB[IN];
    const float* xbase = x + (long)b * TN * IN;

#define LOADP(P, ck) do {                                                     \
        const float* _s = xbase + (long)((ck) * CT + lane) * IN;              \
        _Pragma("unroll")                                                     \
        for (int _i = 0; _i < IN; ++_i) P[_i] = _s[_i];                       \
    } while (0)
#define COMMITP(P) do {                                                       \
        _Pragma("unroll")                                                     \
        for (int _i = 0; _i < IN; ++_i) xs[_i][grp][lane] = P[_i];            \
    } while (0)
// one projection quarter-step: 4 timesteps (2 xd pairs) for this chain
#define PROJQ(bufn, q) do {                                                   \
        float2 _aA = bias2, _aB = bias2;                                      \
        _Pragma("unroll")                                                     \
        for (int _i = 0; _i < IN; ++_i) {                                     \
            const float4 _xv = *(const float4*)&xs[_i][grp][(q)];             \
            _aA = pkfma(w2[_i], make_float2(_xv.x, _xv.y), _aA);              \
            _aB = pkfma(w2[_i], make_float2(_xv.z, _xv.w), _aB);              \
        }                                                                     \
        xd2[bufn][((q) >> 1) + 0][l64] = _aA;                                 \
        xd2[bufn][((q) >> 1) + 1][l64] = _aB;                                 \
    } while (0)
// one LSTM step; xr is the kmul-scaled gate pre-activation (x-part + bias)
#define STEP(xr) do {                                                         \
        float _s0 = fmaf(whh[0], h0, (xr));                                   \
        _s0 = fmaf(whh[1], h1, _s0);                                          \
        _s0 = fmaf(whh[2], h2, _s0);                                          \
        _s0 = fmaf(whh[3], h3, _s0);                                          \
        float _s1 = whh[4] * h4;                                              \
        _s1 = fmaf(whh[5], h5, _s1);                                          \
        _s1 = fmaf(whh[6], h6, _s1);                                          \
        const float _sg = _s0 + _s1;                                          \
        float _e   = __builtin_amdgcn_exp2f(_sg);                             \
        float _val = fmaf(__builtin_amdgcn_rcpf(1.0f + _e), sc, offc);        \
        const float _iv = QB(_val, 0);                                        \
        const float _fv = QB(_val, 1);                                        \
        const float _gv = QB(_val, 2);                                        \
        const float _ov = QB(_val, 3);                                        \
        cval = fmaf(_fv, cval, _iv * _gv);                                    \
        float _e2 = __builtin_amdgcn_exp2f(K2 * cval);                        \
        float _th = fmaf(__builtin_amdgcn_rcpf(1.0f + _e2), 2.0f, -1.0f);     \
        const float _hq = _ov * _th;                                          \
        h0 = SWZ(_hq, (0  << 5));                                             \
        h1 = SWZ(_hq, (4  << 5));                                             \
        h2 = SWZ(_hq, (8  << 5));                                             \
        h3 = SWZ(_hq, (12 << 5));                                             \
        h4 = SWZ(_hq, (16 << 5));                                             \
        h5 = SWZ(_hq, (20 << 5));                                             \
        h6 = SWZ(_hq, (24 << 5));                                             \
    } while (0)
// one chunk: recurrence on xd2[ck&1] with NEXT chunk's staging+projection
// interleaved into the trans shadows (all same-wave; no barriers anywhere)
#define CHUNK(ck, PC, PN) do {                                                \
        const int _cur = (ck) & 1, _nxt = _cur ^ 1;                           \
        const bool _hasN  = (ck) + 1 < NCK;                                   \
        const bool _hasNN = (ck) + 2 < NCK;                                   \
        if (_hasN)  COMMITP(PC);            /* chunk ck+1 regs -> xs */       \
        if (_hasNN) LOADP(PN, (ck) + 2);    /* chunk ck+2 global -> regs */   \
        _Pragma("unroll")                                                     \
        for (int _sb = 0; _sb < 4; ++_sb) {                                   \
            float2 _xr0 = xd2[_cur][_sb * 4 + 0][l64];                        \
            float2 _xr1 = xd2[_cur][_sb * 4 + 1][l64];                        \
            float2 _xr2 = xd2[_cur][_sb * 4 + 2][l64];                        \
            float2 _xr3 = xd2[_cur][_sb * 4 + 3][l64];                        \
            if (_hasN) {                    /* filler: proj chunk ck+1 */     \
                PROJQ(_nxt, _sb * 8);                                         \
                PROJQ(_nxt, _sb * 8 + 4);                                     \
            }                                                                 \
            STEP(_xr0.x); STEP(_xr0.y);                                       \
            STEP(_xr1.x); STEP(_xr1.y);                                       \
            STEP(_xr2.x); STEP(_xr2.y);                                       \
            STEP(_xr3.x); STEP(_xr3.y);                                       \
        }                                                                     \
    } while (0)

    // ---------------- prologue: chunk 0 on-chain, prefetch chunk 1 ----------------
    LOADP(pA, 0);
    COMMITP(pA);
    LOADP(pA, 1);                 // WAR on pA is register-ordered by compiler
#pragma unroll
    for (int q = 0; q < CT; q += 4) PROJQ(0, q);

    // ---------------- main loop: 16 chunks, ping-pong prefetch regs ----------------
#pragma unroll
    for (int ckb = 0; ckb < NCK / 2; ++ckb) {
        CHUNK(2 * ckb,     pA, pB);
        CHUNK(2 * ckb + 1, pB, pA);
    }

    // ---------------- epilogue: relu -> fc1(512x7) -> relu -> fc(1x512) ----------
    float hb[HN] = { fmaxf(h0,0.f), fmaxf(h1,0.f), fmaxf(h2,0.f), fmaxf(h3,0.f),
                     fmaxf(h4,0.f), fmaxf(h5,0.f), fmaxf(h6,0.f) };

    float acc = 0.0f;
#pragma unroll
    for (int k = 0; k < FFD / 32; ++k) {
        const int r = lane + (k << 5);
        float s = fc1_b[r];
#pragma unroll
        for (int j = 0; j < HN; ++j) s = fmaf(fc1_w[r * HN + j], hb[j], s);
        s = fmaxf(s, 0.0f);
        acc = fmaf(fc_w[r], s, acc);
    }
#pragma unroll
    for (int o = 16; o >= 1; o >>= 1) acc += __shfl_xor(acc, o, 32);
    if (lane == 0) out[b] = acc + fc_b[0];
}

extern "C" void kernel_launch(void* const* d_in, const int* in_sizes, int n_in,
                              void* d_out, int out_size, void* d_ws, size_t ws_size,
                              hipStream_t stream) {
    const float* x     = (const float*)d_in[0];
    const float* w_ih  = (const float*)d_in[1];
    const float* w_hh  = (const float*)d_in[2];
    const float* b_ih  = (const float*)d_in[3];
    const float* b_hh  = (const float*)d_in[4];
    const float* fc1_w = (const float*)d_in[5];
    const float* fc1_b = (const float*)d_in[6];
    const float* fc_w  = (const float*)d_in[7];
    const float* fc_b  = (const float*)d_in[8];
    float* out = (float*)d_out;

    dim3 grid(BB / 2);   // 2048 single-wave blocks, 2 chains each, no barriers
    dim3 block(64);
    hipLaunchKernelGGL(lstm_fused, grid, block, 0, stream,
                       x, w_ih, w_hh, b_ih, b_hh, fc1_w, fc1_b, fc_w, fc_b, out);
}